// Round 5
// baseline (83.448 us; speedup 1.0000x reference)
//
#include <hip/hip_runtime.h>
#include <hip/hip_bf16.h>

#define BTOT 128     // B*T
#define NN   512
#define FIN  128
#define FOUT 64

typedef __attribute__((ext_vector_type(8))) short bf16x8;
typedef __attribute__((ext_vector_type(4))) float f32x4;

static __device__ inline ushort f2bf(float f) {
    __hip_bfloat16 h = __float2bfloat16(f);
    return *(ushort*)&h;
}
static __device__ inline float bf2f(ushort u) {
    uint v = (uint)u << 16;
    return __uint_as_float(v);
}

// ---------- P: prep W split (blocks 256..287) + cd pack (blocks 0..255) ----------
// cd word: hi16 = bf16(w*log2e) if conn else 0; lo16 = bf16(-inf) if (!conn && w>0) else 0.
// p = exp2(fma(c, leaky(s), d)) reproduces all ref corner cases (incl. w==0).
__global__ void k_prep(const float* __restrict__ W, const int* __restrict__ adj,
                       const float* __restrict__ we, ushort* __restrict__ Whi,
                       ushort* __restrict__ Wlo, uint* __restrict__ cd) {
    int b = blockIdx.x;
    if (b >= 256) {       // W split: 8192 elems over 32 blocks
        int i = (b - 256) * 256 + threadIdx.x;
        float w = W[i];
        ushort hi = f2bf(w);
        Whi[i] = hi;
        Wlo[i] = f2bf(w - bf2f(hi));
        return;
    }
    int i = (b * 256 + threadIdx.x) * 4;     // 262144 words
    int4   a4 = *(const int4*)&adj[i];
    float4 w4 = *(const float4*)&we[i];
    uint o[4];
#pragma unroll
    for (int e = 0; e < 4; ++e) {
        bool  cn = ((const int*)&a4)[e] > 0;
        float w  = ((const float*)&w4)[e];
        ushort cb = cn ? f2bf(w * 1.44269504f) : (ushort)0;
        ushort db = (!cn && w > 0.f) ? (ushort)0xFF80 : (ushort)0;   // -inf bf16
        o[e] = ((uint)cb << 16) | db;
    }
    *(uint4*)&cd[i] = *(uint4*)&o[0];
}

// ---------- A: h = x @ W^T via bf16x3 MFMA; emit ht bf16 [bt][o][n], src, dst ----
// grid (8, 128), 256 threads = 4 waves; no LDS, no barriers.
__global__ void k_feat(const float* __restrict__ x, const ushort* __restrict__ Whi,
                       const ushort* __restrict__ Wlo, const float* __restrict__ a,
                       ushort* __restrict__ ht, float* __restrict__ srcv,
                       float* __restrict__ dstv) {
    const int t    = threadIdx.x;
    const int bt   = blockIdx.y;
    const int wv   = t >> 6, lane = t & 63;
    const int r    = lane & 15;          // A-row / B-col within 16; C/D col
    const int kc   = lane >> 4;          // k-chunk; C/D row group
    const int n0   = blockIdx.x * 64 + wv * 16;

    const float* xrow = x + ((long)bt * NN + n0 + r) * FIN;

    f32x4 acc[4] = {{0,0,0,0},{0,0,0,0},{0,0,0,0},{0,0,0,0}};

#pragma unroll
    for (int ks = 0; ks < 4; ++ks) {
        float4 xa = *(const float4*)&xrow[ks * 32 + kc * 8];
        float4 xb = *(const float4*)&xrow[ks * 32 + kc * 8 + 4];
        float xv[8] = {xa.x, xa.y, xa.z, xa.w, xb.x, xb.y, xb.z, xb.w};
        bf16x8 Ahi, Alo;
#pragma unroll
        for (int e = 0; e < 8; ++e) {
            ushort h = f2bf(xv[e]);
            Ahi[e] = (short)h;
            Alo[e] = (short)f2bf(xv[e] - bf2f(h));
        }
#pragma unroll
        for (int g = 0; g < 4; ++g) {
            const int wo = (g * 16 + r) * FIN + ks * 32 + kc * 8;
            bf16x8 Bhi = *(const bf16x8*)&Whi[wo];
            bf16x8 Blo = *(const bf16x8*)&Wlo[wo];
            acc[g] = __builtin_amdgcn_mfma_f32_16x16x32_bf16(Ahi, Bhi, acc[g], 0, 0, 0);
            acc[g] = __builtin_amdgcn_mfma_f32_16x16x32_bf16(Alo, Bhi, acc[g], 0, 0, 0);
            acc[g] = __builtin_amdgcn_mfma_f32_16x16x32_bf16(Ahi, Blo, acc[g], 0, 0, 0);
        }
    }

    // src/dst: per-row dot with a1/a2, reduce across the 16 tx lanes
    float a1g[4], a2g[4];
#pragma unroll
    for (int g = 0; g < 4; ++g) {
        a1g[g] = a[g * 16 + r];
        a2g[g] = a[FOUT + g * 16 + r];
    }
    f32x4 s1v = {0,0,0,0}, s2v = {0,0,0,0};
#pragma unroll
    for (int g = 0; g < 4; ++g)
#pragma unroll
        for (int reg = 0; reg < 4; ++reg) {
            s1v[reg] += acc[g][reg] * a1g[g];
            s2v[reg] += acc[g][reg] * a2g[g];
        }
#pragma unroll
    for (int off = 8; off; off >>= 1)
#pragma unroll
        for (int reg = 0; reg < 4; ++reg) {
            s1v[reg] += __shfl_down(s1v[reg], off, 16);
            s2v[reg] += __shfl_down(s2v[reg], off, 16);
        }
    if (r == 0) {
        float4 o1 = make_float4(s1v[0], s1v[1], s1v[2], s1v[3]);
        float4 o2 = make_float4(s2v[0], s2v[1], s2v[2], s2v[3]);
        *(float4*)&srcv[bt * NN + n0 + kc * 4] = o1;
        *(float4*)&dstv[bt * NN + n0 + kc * 4] = o2;
    }

    // ht[bt][o][n] bf16
#pragma unroll
    for (int g = 0; g < 4; ++g) {
        uint2 pk;
        pk.x = (uint)f2bf(acc[g][0]) | ((uint)f2bf(acc[g][1]) << 16);
        pk.y = (uint)f2bf(acc[g][2]) | ((uint)f2bf(acc[g][3]) << 16);
        *(uint2*)&ht[(long)bt * (FOUT * NN) + (g * 16 + r) * NN + n0 + kc * 4] = pk;
    }
}

// ---------- B: fused att + bf16 MFMA PV, bt-batched ----------
// grid 256 = btg(0..31) * 8 + it(0..7)  => XCD = it; all 32 blocks of an XCD
// reuse the same 131KB cd slice. 512 threads: wave-half h processes bt0+2h+bs
// (bs=0,1 serial). Both halves read identical cd addresses (L1 broadcast).
__global__ __launch_bounds__(512)
void k_attn(const ushort* __restrict__ ht, const float* __restrict__ srcv,
            const float* __restrict__ dstv, const uint* __restrict__ cd,
            float* __restrict__ out) {
    __shared__ ushort ps[2][64 * 72];   // p tile bf16 [i][k]
    __shared__ ushort hs[2][64 * 72];   // h^T tile bf16 [o][k]
    __shared__ float dst_s[2][NN];
    __shared__ float src_s[2][64];

    const int t    = threadIdx.x;
    const int bid  = blockIdx.x;
    const int i0   = (bid & 7) << 6;
    const int bt0  = (bid >> 3) << 2;
    const int lane = t & 63;
    const int wvh  = (t >> 6) & 3;      // wave within half
    const int half = t >> 8;
    const int lw   = t & 255;           // thread within half

    const int pi = lw >> 2;             // p-compute: row
    const int pj = (lw & 3) * 16;       // p-compute: col base
    const uint* cdr = cd + (i0 + pi) * NN;

    bf16x8 ones;
#pragma unroll
    for (int j = 0; j < 8; ++j) ones[j] = (short)0x3F80;   // bf16 1.0

    const int arow = (wvh * 16 + (lane & 15)) * 72;
    const int koff = (lane >> 4) * 8;

    for (int bs = 0; bs < 2; ++bs) {
        const int bt = bt0 + half * 2 + bs;
        if (lw < 64) src_s[half][lw] = srcv[bt * NN + i0 + lw];
#pragma unroll
        for (int r = lw; r < NN; r += 256) dst_s[half][r] = dstv[bt * NN + r];
        __syncthreads();

        const float si = src_s[half][pi];
        const ushort* htb = ht + (long)bt * (FOUT * NN);

        f32x4 acc0 = {0,0,0,0}, acc1 = {0,0,0,0}, acc2 = {0,0,0,0},
              acc3 = {0,0,0,0}, accd = {0,0,0,0};

        for (int jt = 0; jt < 8; ++jt) {
            const int j0 = jt * 64;

            // stage hs (256 threads x 32B = 8KB tile)
#pragma unroll
            for (int q = 0; q < 2; ++q) {
                int idx = 2 * lw + q;
                int row = idx >> 3, c8 = idx & 7;
                float4 v = *(const float4*)&htb[row * NN + j0 + c8 * 8];
                *(float4*)&hs[half][row * 72 + c8 * 8] = v;
            }

            // p = exp2(fma(c, leaky(si+dj), d)), 16 elems/thread
            ushort pu[16];
#pragma unroll
            for (int q = 0; q < 4; ++q) {
                uint4  c4  = *(const uint4*)&cdr[j0 + pj + 4 * q];
                float4 dv4 = *(const float4*)&dst_s[half][j0 + pj + 4 * q];
#pragma unroll
                for (int e = 0; e < 4; ++e) {
                    uint  wd = ((const uint*)&c4)[e];
                    float cf = __uint_as_float(wd & 0xFFFF0000u);
                    float df = __uint_as_float(wd << 16);
                    float s  = si + ((const float*)&dv4)[e];
                    float lr = fmaxf(s, 0.01f * s);
                    pu[4 * q + e] = f2bf(__builtin_amdgcn_exp2f(fmaf(cf, lr, df)));
                }
            }
            *(float4*)&ps[half][pi * 72 + pj]     = *(float4*)&pu[0];
            *(float4*)&ps[half][pi * 72 + pj + 8] = *(float4*)&pu[8];
            __syncthreads();

            // MFMA: wave wvh owns rows 16wvh..+15 of its half's tile
#pragma unroll
            for (int s2 = 0; s2 < 2; ++s2) {
                bf16x8 afr = *(bf16x8*)&ps[half][arow + s2 * 32 + koff];
                bf16x8 b0  = *(bf16x8*)&hs[half][( 0 + (lane & 15)) * 72 + s2 * 32 + koff];
                bf16x8 b1  = *(bf16x8*)&hs[half][(16 + (lane & 15)) * 72 + s2 * 32 + koff];
                bf16x8 b2  = *(bf16x8*)&hs[half][(32 + (lane & 15)) * 72 + s2 * 32 + koff];
                bf16x8 b3  = *(bf16x8*)&hs[half][(48 + (lane & 15)) * 72 + s2 * 32 + koff];
                acc0 = __builtin_amdgcn_mfma_f32_16x16x32_bf16(afr, b0, acc0, 0, 0, 0);
                acc1 = __builtin_amdgcn_mfma_f32_16x16x32_bf16(afr, b1, acc1, 0, 0, 0);
                acc2 = __builtin_amdgcn_mfma_f32_16x16x32_bf16(afr, b2, acc2, 0, 0, 0);
                acc3 = __builtin_amdgcn_mfma_f32_16x16x32_bf16(afr, b3, acc3, 0, 0, 0);
                accd = __builtin_amdgcn_mfma_f32_16x16x32_bf16(afr, ones, accd, 0, 0, 0);
            }
            __syncthreads();
        }

        // epilogue for this bt
        const int orow = wvh * 16 + (lane >> 4) * 4;
        const int ocol = lane & 15;
        float* ob = out + ((long)bt * NN + i0) * FOUT;
#pragma unroll
        for (int reg = 0; reg < 4; ++reg) {
            float inv = 1.0f / accd[reg];
            ob[(orow + reg) * FOUT +  0 + ocol] = acc0[reg] * inv;
            ob[(orow + reg) * FOUT + 16 + ocol] = acc1[reg] * inv;
            ob[(orow + reg) * FOUT + 32 + ocol] = acc2[reg] * inv;
            ob[(orow + reg) * FOUT + 48 + ocol] = acc3[reg] * inv;
        }
    }
}

extern "C" void kernel_launch(void* const* d_in, const int* in_sizes, int n_in,
                              void* d_out, int out_size, void* d_ws, size_t ws_size,
                              hipStream_t stream) {
    const float* x      = (const float*)d_in[0];
    const float* W      = (const float*)d_in[1];
    const float* a      = (const float*)d_in[2];
    const int*   adj    = (const int*)d_in[3];
    const float* adj_we = (const float*)d_in[4];
    float* out = (float*)d_out;

    ushort* Whi  = (ushort*)d_ws;                      // 8192 bf16
    ushort* Wlo  = Whi + FOUT * FIN;                   // 8192 bf16
    ushort* ht   = Wlo + FOUT * FIN;                   // 128*64*512 bf16
    float*  srcv = (float*)(ht + BTOT * FOUT * NN);    // 65536 fp32
    float*  dstv = srcv + BTOT * NN;                   // 65536 fp32
    uint*   cdw  = (uint*)(dstv + BTOT * NN);          // 262144 words

    hipLaunchKernelGGL(k_prep, dim3(288), dim3(256), 0, stream,
                       W, adj, adj_we, Whi, Wlo, cdw);
    hipLaunchKernelGGL(k_feat, dim3(8, 128), dim3(256), 0, stream,
                       x, Whi, Wlo, a, ht, srcv, dstv);
    hipLaunchKernelGGL(k_attn, dim3(256), dim3(512), 0, stream,
                       ht, srcv, dstv, cdw, out);
}

// Round 6
// 51.067 us; speedup vs baseline: 1.6341x; 1.6341x over previous
//
#include <hip/hip_runtime.h>
#include <hip/hip_bf16.h>

#define BTOT 128     // B*T
#define NN   512
#define FIN  128
#define FOUT 64

typedef __attribute__((ext_vector_type(8))) short bf16x8;
typedef __attribute__((ext_vector_type(4))) float f32x4;

static __device__ inline ushort f2bf(float f) {
    __hip_bfloat16 h = __float2bfloat16(f);
    return *(ushort*)&h;
}
static __device__ inline float bf2f(ushort u) {
    uint v = (uint)u << 16;
    return __uint_as_float(v);
}

// ---------- P: prep W split (blocks 256..287) + cd pack (blocks 0..255) ----------
// cd word: hi16 = bf16(w*log2e) if conn else 0; lo16 = bf16(-inf) if (!conn && w>0) else 0.
// p = exp2(fma(c, leaky(s), d)) reproduces all ref corner cases (incl. w==0).
__global__ void k_prep(const float* __restrict__ W, const int* __restrict__ adj,
                       const float* __restrict__ we, ushort* __restrict__ Whi,
                       ushort* __restrict__ Wlo, uint* __restrict__ cd) {
    int b = blockIdx.x;
    if (b >= 256) {       // W split: 8192 elems over 32 blocks
        int i = (b - 256) * 256 + threadIdx.x;
        float w = W[i];
        ushort hi = f2bf(w);
        Whi[i] = hi;
        Wlo[i] = f2bf(w - bf2f(hi));
        return;
    }
    int i = (b * 256 + threadIdx.x) * 4;     // 262144 words
    int4   a4 = *(const int4*)&adj[i];
    float4 w4 = *(const float4*)&we[i];
    uint o[4];
#pragma unroll
    for (int e = 0; e < 4; ++e) {
        bool  cn = ((const int*)&a4)[e] > 0;
        float w  = ((const float*)&w4)[e];
        ushort cb = cn ? f2bf(w * 1.44269504f) : (ushort)0;
        ushort db = (!cn && w > 0.f) ? (ushort)0xFF80 : (ushort)0;   // -inf bf16
        o[e] = ((uint)cb << 16) | db;
    }
    *(uint4*)&cd[i] = *(uint4*)&o[0];
}

// ---------- A: h = x @ W^T via bf16x3 MFMA; emit ht bf16 [bt][o][n], src, dst ----
// grid (8, 128), 256 threads = 4 waves; no LDS, no barriers.
// A-operand split is exact-truncation: hi=trunc_bf16(x) (1 op), r=x-hi (exact,
// Sterbenz), lo=trunc_bf16(r); residual <= 2^-16 |x|.
__global__ void k_feat(const float* __restrict__ x, const ushort* __restrict__ Whi,
                       const ushort* __restrict__ Wlo, const float* __restrict__ a,
                       ushort* __restrict__ ht, float* __restrict__ srcv,
                       float* __restrict__ dstv) {
    const int t    = threadIdx.x;
    const int bt   = blockIdx.y;
    const int wv   = t >> 6, lane = t & 63;
    const int r    = lane & 15;          // A-row / B-col within 16; C/D col
    const int kc   = lane >> 4;          // k-chunk; C/D row group
    const int n0   = blockIdx.x * 64 + wv * 16;

    const float* xrow = x + ((long)bt * NN + n0 + r) * FIN;

    f32x4 acc[4] = {{0,0,0,0},{0,0,0,0},{0,0,0,0},{0,0,0,0}};

#pragma unroll
    for (int ks = 0; ks < 4; ++ks) {
        float4 xa = *(const float4*)&xrow[ks * 32 + kc * 8];
        float4 xb = *(const float4*)&xrow[ks * 32 + kc * 8 + 4];
        float xv[8] = {xa.x, xa.y, xa.z, xa.w, xb.x, xb.y, xb.z, xb.w};
        bf16x8 Ahi, Alo;
#pragma unroll
        for (int e = 0; e < 8; ++e) {
            uint b = __float_as_uint(xv[e]);
            float hf = __uint_as_float(b & 0xFFFF0000u);
            Ahi[e] = (short)(b >> 16);
            float rr = xv[e] - hf;                       // exact
            Alo[e] = (short)(__float_as_uint(rr) >> 16); // trunc
        }
#pragma unroll
        for (int g = 0; g < 4; ++g) {
            const int wo = (g * 16 + r) * FIN + ks * 32 + kc * 8;
            bf16x8 Bhi = *(const bf16x8*)&Whi[wo];
            bf16x8 Blo = *(const bf16x8*)&Wlo[wo];
            acc[g] = __builtin_amdgcn_mfma_f32_16x16x32_bf16(Ahi, Bhi, acc[g], 0, 0, 0);
            acc[g] = __builtin_amdgcn_mfma_f32_16x16x32_bf16(Alo, Bhi, acc[g], 0, 0, 0);
            acc[g] = __builtin_amdgcn_mfma_f32_16x16x32_bf16(Ahi, Blo, acc[g], 0, 0, 0);
        }
    }

    // src/dst: per-row dot with a1/a2, reduce across the 16 tx lanes
    float a1g[4], a2g[4];
#pragma unroll
    for (int g = 0; g < 4; ++g) {
        a1g[g] = a[g * 16 + r];
        a2g[g] = a[FOUT + g * 16 + r];
    }
    f32x4 s1v = {0,0,0,0}, s2v = {0,0,0,0};
#pragma unroll
    for (int g = 0; g < 4; ++g)
#pragma unroll
        for (int reg = 0; reg < 4; ++reg) {
            s1v[reg] += acc[g][reg] * a1g[g];
            s2v[reg] += acc[g][reg] * a2g[g];
        }
#pragma unroll
    for (int off = 8; off; off >>= 1)
#pragma unroll
        for (int reg = 0; reg < 4; ++reg) {
            s1v[reg] += __shfl_down(s1v[reg], off, 16);
            s2v[reg] += __shfl_down(s2v[reg], off, 16);
        }
    if (r == 0) {
        float4 o1 = make_float4(s1v[0], s1v[1], s1v[2], s1v[3]);
        float4 o2 = make_float4(s2v[0], s2v[1], s2v[2], s2v[3]);
        *(float4*)&srcv[bt * NN + n0 + kc * 4] = o1;
        *(float4*)&dstv[bt * NN + n0 + kc * 4] = o2;
    }

    // ht[bt][o][n] bf16
#pragma unroll
    for (int g = 0; g < 4; ++g) {
        uint2 pk;
        pk.x = (uint)f2bf(acc[g][0]) | ((uint)f2bf(acc[g][1]) << 16);
        pk.y = (uint)f2bf(acc[g][2]) | ((uint)f2bf(acc[g][3]) << 16);
        *(uint2*)&ht[(long)bt * (FOUT * NN) + (g * 16 + r) * NN + n0 + kc * 4] = pk;
    }
}

// ---------- B: fused att + bf16 MFMA PV ----------
// 1D grid 1024: bid = it*128 + bt  =>  XCD = bid%8 = bt%8 (128 % 8 == 0).
// Per XCD: 16 bt's x 8 i-tiles -> working set 1MB ht + 1MB cd, both L2-resident.
__global__ void k_attn(const ushort* __restrict__ ht, const float* __restrict__ srcv,
                       const float* __restrict__ dstv, const uint* __restrict__ cd,
                       float* __restrict__ out) {
    __shared__ ushort ps[64 * 72];   // p tile bf16 [i][k], stride 72
    __shared__ ushort hs[64 * 72];   // h^T tile bf16 [o][k], stride 72
    __shared__ float dst_s[NN];
    __shared__ float src_s[64];

    const int t    = threadIdx.x;
    const int bid  = blockIdx.x;
    const int bt   = bid & 127;
    const int i0   = (bid >> 7) << 6;
    const int lane = t & 63;
    const int wv   = t >> 6;

    if (t < 64) src_s[t] = srcv[bt * NN + i0 + t];
    for (int r = t; r < NN; r += 256) dst_s[r] = dstv[bt * NN + r];

    const int pi = t >> 2;           // p-compute: row
    const int pj = (t & 3) * 16;     // p-compute: col base (16 consecutive j)
    const uint* cdr   = cd + (i0 + pi) * NN;
    const ushort* htb = ht + (long)bt * (FOUT * NN);

    f32x4 acc0 = {0,0,0,0}, acc1 = {0,0,0,0}, acc2 = {0,0,0,0},
          acc3 = {0,0,0,0}, accd = {0,0,0,0};

    bf16x8 ones;
#pragma unroll
    for (int j = 0; j < 8; ++j) ones[j] = (short)0x3F80;   // bf16 1.0

    __syncthreads();
    const float si = src_s[pi];

    const int arow = (wv * 16 + (lane & 15)) * 72;   // A-frag row base
    const int koff = (lane >> 4) * 8;                // k-chunk within frag

    for (int jt = 0; jt < 8; ++jt) {
        const int j0 = jt * 64;

        // stage hs (bf16, contiguous 16B per lane)
#pragma unroll
        for (int q = 0; q < 2; ++q) {
            int idx = 2 * t + q;             // 0..511
            int row = idx >> 3, c8 = idx & 7;
            float4 v = *(const float4*)&htb[row * NN + j0 + c8 * 8];
            *(float4*)&hs[row * 72 + c8 * 8] = v;
        }

        // p = exp2(fma(c, leaky(si+dj), d)), 16 elems/thread, pack bf16
        ushort pu[16];
#pragma unroll
        for (int q = 0; q < 4; ++q) {
            uint4  c4  = *(const uint4*)&cdr[j0 + pj + 4 * q];
            float4 dv4 = *(const float4*)&dst_s[j0 + pj + 4 * q];
#pragma unroll
            for (int e = 0; e < 4; ++e) {
                uint  wd = ((const uint*)&c4)[e];
                float cf = __uint_as_float(wd & 0xFFFF0000u);
                float df = __uint_as_float(wd << 16);
                float s  = si + ((const float*)&dv4)[e];
                float lr = fmaxf(s, 0.01f * s);
                pu[4 * q + e] = f2bf(__builtin_amdgcn_exp2f(fmaf(cf, lr, df)));
            }
        }
        *(float4*)&ps[pi * 72 + pj]     = *(float4*)&pu[0];
        *(float4*)&ps[pi * 72 + pj + 8] = *(float4*)&pu[8];
        __syncthreads();

        // MFMA: wave wv owns rows 16wv..16wv+15, all 64 o-cols + den
#pragma unroll
        for (int s2 = 0; s2 < 2; ++s2) {
            bf16x8 afr = *(bf16x8*)&ps[arow + s2 * 32 + koff];
            bf16x8 b0  = *(bf16x8*)&hs[( 0 + (lane & 15)) * 72 + s2 * 32 + koff];
            bf16x8 b1  = *(bf16x8*)&hs[(16 + (lane & 15)) * 72 + s2 * 32 + koff];
            bf16x8 b2  = *(bf16x8*)&hs[(32 + (lane & 15)) * 72 + s2 * 32 + koff];
            bf16x8 b3  = *(bf16x8*)&hs[(48 + (lane & 15)) * 72 + s2 * 32 + koff];
            acc0 = __builtin_amdgcn_mfma_f32_16x16x32_bf16(afr, b0, acc0, 0, 0, 0);
            acc1 = __builtin_amdgcn_mfma_f32_16x16x32_bf16(afr, b1, acc1, 0, 0, 0);
            acc2 = __builtin_amdgcn_mfma_f32_16x16x32_bf16(afr, b2, acc2, 0, 0, 0);
            acc3 = __builtin_amdgcn_mfma_f32_16x16x32_bf16(afr, b3, acc3, 0, 0, 0);
            accd = __builtin_amdgcn_mfma_f32_16x16x32_bf16(afr, ones, accd, 0, 0, 0);
        }
        __syncthreads();
    }

    // epilogue: C/D layout col=lane&15, row=(lane>>4)*4+reg; den in accd same slots
    const int orow = wv * 16 + (lane >> 4) * 4;
    const int ocol = lane & 15;
    float* ob = out + ((long)bt * NN + i0) * FOUT;
#pragma unroll
    for (int reg = 0; reg < 4; ++reg) {
        float inv = 1.0f / accd[reg];
        ob[(orow + reg) * FOUT +  0 + ocol] = acc0[reg] * inv;
        ob[(orow + reg) * FOUT + 16 + ocol] = acc1[reg] * inv;
        ob[(orow + reg) * FOUT + 32 + ocol] = acc2[reg] * inv;
        ob[(orow + reg) * FOUT + 48 + ocol] = acc3[reg] * inv;
    }
}

extern "C" void kernel_launch(void* const* d_in, const int* in_sizes, int n_in,
                              void* d_out, int out_size, void* d_ws, size_t ws_size,
                              hipStream_t stream) {
    const float* x      = (const float*)d_in[0];
    const float* W      = (const float*)d_in[1];
    const float* a      = (const float*)d_in[2];
    const int*   adj    = (const int*)d_in[3];
    const float* adj_we = (const float*)d_in[4];
    float* out = (float*)d_out;

    ushort* Whi  = (ushort*)d_ws;                      // 8192 bf16
    ushort* Wlo  = Whi + FOUT * FIN;                   // 8192 bf16
    ushort* ht   = Wlo + FOUT * FIN;                   // 128*64*512 bf16
    float*  srcv = (float*)(ht + BTOT * FOUT * NN);    // 65536 fp32
    float*  dstv = srcv + BTOT * NN;                   // 65536 fp32
    uint*   cdw  = (uint*)(dstv + BTOT * NN);          // 262144 words

    hipLaunchKernelGGL(k_prep, dim3(288), dim3(256), 0, stream,
                       W, adj, adj_we, Whi, Wlo, cdw);
    hipLaunchKernelGGL(k_feat, dim3(8, 128), dim3(256), 0, stream,
                       x, Whi, Wlo, a, ht, srcv, dstv);
    hipLaunchKernelGGL(k_attn, dim3(1024), dim3(256), 0, stream,
                       ht, srcv, dstv, cdw, out);
}